// Round 10
// baseline (384.415 us; speedup 1.0000x reference)
//
#include <hip/hip_runtime.h>

typedef unsigned short ushort_t;
typedef _Float16 half8 __attribute__((ext_vector_type(8)));
typedef float f32x4 __attribute__((ext_vector_type(4)));

constexpr int NN  = 30000;
constexpr int EE  = 480000;
constexpr int NEXM = 64;
constexpr int ATB = 32;                 // dst atoms owned per mega_pass block
constexpr int NBLK = (NN + ATB - 1) / ATB;  // 938 (last block: tile1 invalid)
constexpr int NSB = (NN + 255) / 256;   // scan blocks (118)
constexpr int NBINS = 2048;             // W(d) table bins over [0,10]
constexpr int TROWS = 2064;             // 129 tiles * 16 rows (>= NBINS+2)

#define MFMA16(a,b,c) __builtin_amdgcn_mfma_f32_16x16x32_f16((a),(b),(c),0,0,0)
#define LDS_ADD(p,v) __hip_atomic_fetch_add((p),(v),__ATOMIC_RELAXED,__HIP_MEMORY_SCOPE_WORKGROUP)
#define LGKM_WAIT asm volatile("s_waitcnt lgkmcnt(0)" ::: "memory")

__device__ __forceinline__ float fast_tanh(float x){
  float e2 = __builtin_amdgcn_exp2f(x * 2.885390081777927f);
  return 1.f - 2.f * __builtin_amdgcn_rcpf(e2 + 1.f);
}
__device__ __forceinline__ ushort_t f2h(float v){
  union { _Float16 h; ushort_t s; } cv; cv.h = (_Float16)v; return cv.s;
}

// ---------------- F1: weight pre-swizzle  ||  edge histogram  ||  zero out ----
__global__ __launch_bounds__(256) void fused_prep(
  const float* __restrict__ fw1, const float* __restrict__ fb1,
  const float* __restrict__ fw2, const float* __restrict__ l1w,
  const float* __restrict__ l2w, const float* __restrict__ bw,
  const float* __restrict__ ow1, ushort_t* __restrict__ frags,
  const int* __restrict__ ei, int* __restrict__ cnt, float* __restrict__ out)
{
  const int bid = blockIdx.x;
  if (bid < 896){
    if (bid == 0 && threadIdx.x < NEXM) out[threadIdx.x] = 0.f;
    int u = bid*256 + threadIdx.x;
    float val;
    if (u < 24576){                       // w1T A-frags, K padded 50->64, row50=bias
      int b = u >> 13; int v = u & 8191;
      int j = v & 7, lane = (v>>3)&63, fid = v>>9;     // fid = mt*2+ks
      int mt = fid>>1, ks = fid&1;
      int f1 = mt*16 + (lane&15);
      int k  = ks*32 + ((lane>>4)&3)*8 + j;
      val = (k < 50) ? fw1[(b*50 + k)*128 + f1] : (k == 50 ? fb1[b*128 + f1] : 0.f);
    } else if (u < 73728){                // w2T A-frags (A[m=f2][k=f1]), fid = mt*4+ks
      int v = u - 24576; int b = v >> 14; int v2 = v & 16383;
      int j = v2&7, lane = (v2>>3)&63, fid = v2>>9;
      int mt = fid>>2, ks = fid&3;
      int n = mt*16 + (lane&15);          // f2
      int k = ks*32 + ((lane>>4)&3)*8 + j; // f1
      val = fw2[b*16384 + k*128 + n];
    } else if (u < 221184){               // l2T / blkT / l1T A-frags, fid = mt*4+ks
      int v = u - 73728; int g = v / 49152; int v1 = v - g*49152;
      int b = v1 >> 14; int v2 = v1 & 16383;
      int j = v2&7, lane=(v2>>3)&63, fid=v2>>9;
      int mt = fid>>2, ks = fid&3;
      int n = mt*16 + (lane&15);
      int k = ks*32 + ((lane>>4)&3)*8 + j;
      const float* W = (g==0? l2w : (g==1? bw : l1w));
      val = W[b*16384 + k*128 + n];
    } else {                              // ow1T A-frags [128x64], fid = mt*4+ks
      int v2 = u - 221184;
      int j = v2&7, lane=(v2>>3)&63, fid=v2>>9;
      int mt = fid>>2, ks = fid&3;
      int n = mt*16 + (lane&15);
      int k = ks*32 + ((lane>>4)&3)*8 + j;
      val = ow1[k*64 + n];
    }
    frags[u] = f2h(val);
  } else {
    int e = (bid-896)*256 + threadIdx.x;
    atomicAdd(cnt + ei[EE + e], 1);
  }
}

// ---------------- F2: W(d) table build  ||  scan stage 1 ----------------------
__global__ __launch_bounds__(256) void fused_mid(
  const ushort_t* __restrict__ w1a, const ushort_t* __restrict__ w2a,
  const float* __restrict__ fb2, ushort_t* __restrict__ tab,
  const int* __restrict__ cnt, int* __restrict__ seg, int* __restrict__ bsum)
{
  __shared__ ushort_t st[4*2112];
  const int bid = blockIdx.x;
  if (bid < 99){
    const int wave = threadIdx.x>>6, lane = threadIdx.x&63;
    const int quad = lane>>4, n15 = lane&15;
    const int b = bid / 33, tg = bid % 33;
    const int tile = tg*4 + wave;
    if (tile >= TROWS/16) return;
    const half8* w1v = (const half8*)(w1a + b*8192);
    const half8* w2v = (const half8*)(w2a + b*16384);
    ushort_t* tw = st + wave*2112;
    half8 a1[16];
    #pragma unroll
    for (int i=0;i<16;i++) a1[i] = w1v[i*64 + lane];
    f32x4 b2v[8];
    #pragma unroll
    for (int mt=0;mt<8;mt++) b2v[mt] = *(const f32x4*)(fb2 + b*128 + mt*16 + quad*4);
    const f32x4 zero4 = {0.f,0.f,0.f,0.f};
    const float dd = 10.f/49.f;
    const float coefl2 = (-0.5f/(dd*dd)) * 1.4426950408889634f;
    const float dbin = 10.f/(float)NBINS;

    float de = (float)(tile*16 + n15) * dbin;
    float Cv = (de < 10.f) ? 0.5f*(cosf(de*0.31415926535897931f)+1.f) : 0.f;
    half8 rb0, rb1;
    #pragma unroll
    for (int j=0;j<8;j++){
      int k0 = quad*8 + j;
      float t0 = de - (float)k0*dd;
      rb0[j] = (_Float16)__builtin_amdgcn_exp2f(coefl2*t0*t0);
      int k1 = 32 + quad*8 + j;
      float v1;
      if (k1 < 50){ float t1 = de - (float)k1*dd; v1 = __builtin_amdgcn_exp2f(coefl2*t1*t1); }
      else v1 = (k1 == 50) ? 1.f : 0.f;
      rb1[j] = (_Float16)v1;
    }
    f32x4 acc1[8];
    #pragma unroll
    for (int mt=0;mt<8;mt++){
      acc1[mt] = MFMA16(a1[mt*2],   rb0, zero4);
      acc1[mt] = MFMA16(a1[mt*2+1], rb1, acc1[mt]);
    }
    #pragma unroll
    for (int mt=0;mt<8;mt++){
      union { ushort_t s[4]; uint2 v; } pk;
      #pragma unroll
      for (int r=0;r<4;r++) pk.s[r] = f2h(fast_tanh(acc1[mt][r]));
      *(uint2*)(tw + n15*132 + mt*16 + quad*4) = pk.v;
    }
    LGKM_WAIT;
    f32x4 acc2[8];
    #pragma unroll
    for (int mt=0;mt<8;mt++) acc2[mt] = zero4;
    #pragma unroll
    for (int ks=0;ks<4;ks++){
      const ushort_t* ra = tw + n15*132 + ks*32 + quad*8;
      union { uint2 v[2]; half8 h16; } cc;
      cc.v[0] = *(const uint2*)(ra);
      cc.v[1] = *(const uint2*)(ra + 4);
      half8 tb = cc.h16;
      #pragma unroll
      for (int mt=0;mt<8;mt++) acc2[mt] = MFMA16(w2v[(mt*4+ks)*64 + lane], tb, acc2[mt]);
    }
    LGKM_WAIT;
    #pragma unroll
    for (int mt=0;mt<8;mt++){
      f32x4 v = acc2[mt] + b2v[mt];
      union { ushort_t s[4]; uint2 q; } pk;
      #pragma unroll
      for (int r=0;r<4;r++) pk.s[r] = f2h(v[r] * Cv);
      *(uint2*)(tw + n15*132 + mt*16 + quad*4) = pk.q;
    }
    LGKM_WAIT;
    ushort_t* dstb = tab + ((size_t)tile*16)*128 + (size_t)b*TROWS*128;
    #pragma unroll
    for (int it=0;it<4;it++){
      int off = it*512 + lane*8;
      uint4 v = *(const uint4*)(tw + (off>>7)*132 + (off&127));
      *(uint4*)(dstb + (size_t)(off>>7)*128 + (off&127)) = v;
    }
  } else {
    // scan1 on block sb = bid-99: per-256-atom EXCLUSIVE scan + block total
    int* ws = (int*)st;
    const int sb = bid - 99;
    int i = sb*256 + threadIdx.x;
    int lane = threadIdx.x & 63, w = threadIdx.x >> 6;
    int v = (i < NN) ? cnt[i] : 0;
    int s = v;
    #pragma unroll
    for (int o=1;o<64;o<<=1){ int t = __shfl_up(s,o,64); if (lane>=o) s += t; }
    if (lane == 63) ws[w] = s;
    __syncthreads();
    int add = 0;
    #pragma unroll
    for (int j=0;j<3;j++) if (w > j) add += ws[j];
    s += add;
    if (i < NN) seg[i] = s - v;
    if (threadIdx.x == 255) bsum[sb] = s;
  }
}

// stage 2: one block scans the 118 block totals -> exclusive offsets (in place)
__global__ __launch_bounds__(128) void scan2(int* __restrict__ bsum)
{
  __shared__ int w0tot;
  int tid = threadIdx.x, lane = tid & 63, w = tid >> 6;
  int v = (tid < NSB) ? bsum[tid] : 0;
  int s = v;
  #pragma unroll
  for (int o=1;o<64;o<<=1){ int t = __shfl_up(s,o,64); if (lane>=o) s += t; }
  if (w == 0 && lane == 63) w0tot = s;
  __syncthreads();
  if (w == 1) s += w0tot;
  if (tid < NSB) bsum[tid] = s - v;
}

// ---------------- F3: scatter_meta (global pos = local slot + bsum)  ||  embed
__global__ __launch_bounds__(256) void fused_tail(
  const float* __restrict__ pos, const int* __restrict__ ei,
  int* __restrict__ seg, const int* __restrict__ bsum, uint2* __restrict__ meta2,
  const int* __restrict__ atype, const float* __restrict__ emb,
  const ushort_t* __restrict__ l1T, float* __restrict__ x, ushort_t* __restrict__ h)
{
  __shared__ float xbuf[4*2112];        // used by embed branch only
  const int bid = blockIdx.x;
  if (bid < 1875){
    int e = bid*256 + threadIdx.x;
    int s = ei[e], d = ei[EE + e];
    float dx = pos[s*3+0]-pos[d*3+0];
    float dy = pos[s*3+1]-pos[d*3+1];
    float dz = pos[s*3+2]-pos[d*3+2];
    float dist = sqrtf(dx*dx+dy*dy+dz*dz + 1e-12f);
    float t = fminf(dist, 10.f) * ((float)NBINS / 10.f);
    int p = atomicAdd(seg + d, 1) + bsum[d>>8];   // local slot + scanned offset
    uint2 m;
    m.x = __float_as_uint(t);
    m.y = (unsigned)s;
    meta2[p] = m;
    return;
  }
  const int vb = bid - 1875;            // 0..511
  const int wave = threadIdx.x>>6, lane = threadIdx.x&63;
  const int quad = lane>>4, n15 = lane&15;
  float* xw = xbuf + wave*2112;
  ushort_t* sw = (ushort_t*)xw;
  const half8* wv = (const half8*)l1T;
  const f32x4 zero4 = {0.f,0.f,0.f,0.f};
  const int ntiles = NN/16;
  const int stride = 512*4;
  for (int tile = vb*4 + wave; tile < ntiles; tile += stride){
    int a0 = tile*16;
    int typ = atype[a0 + n15];
    const f32x4* av = (const f32x4*)(emb + (size_t)typ*128);
    half8 bg[4]; f32x4 xl[4], xh[4];
    #pragma unroll
    for (int ks=0;ks<4;ks++){
      f32x4 lo = av[ks*8 + quad*2];
      f32x4 hi = av[ks*8 + quad*2 + 1];
      xl[ks] = lo; xh[ks] = hi;
      half8 bh;
      #pragma unroll
      for (int i=0;i<4;i++){ bh[i]=(_Float16)lo[i]; bh[4+i]=(_Float16)hi[i]; }
      bg[ks] = bh;
    }
    f32x4 acc[8];
    #pragma unroll
    for (int mt=0;mt<8;mt++) acc[mt] = zero4;
    #pragma unroll
    for (int ks=0;ks<4;ks++){
      #pragma unroll
      for (int mt=0;mt<8;mt++) acc[mt] = MFMA16(wv[(mt*4+ks)*64 + lane], bg[ks], acc[mt]);
    }
    #pragma unroll
    for (int ks=0;ks<4;ks++){
      *(f32x4*)(xw + n15*132 + ks*32 + quad*8)     = xl[ks];
      *(f32x4*)(xw + n15*132 + ks*32 + quad*8 + 4) = xh[ks];
    }
    LGKM_WAIT;
    {
      float* gx = x + (size_t)a0*128;
      #pragma unroll
      for (int it=0;it<8;it++){
        int off2 = it*256 + lane*4;
        f32x4 v = *(const f32x4*)(xw + (off2>>7)*132 + (off2&127));
        *(f32x4*)(gx + off2) = v;
      }
    }
    LGKM_WAIT;
    #pragma unroll
    for (int mt=0;mt<8;mt++){
      union { ushort_t s[4]; uint2 v; } pk;
      #pragma unroll
      for (int r=0;r<4;r++) pk.s[r] = f2h(acc[mt][r]);
      *(uint2*)(sw + n15*132 + mt*16 + quad*4) = pk.v;
    }
    LGKM_WAIT;
    {
      ushort_t* gh = h + (size_t)a0*128;
      #pragma unroll
      for (int it=0;it<4;it++){
        int off2 = it*512 + lane*8;
        uint4 v = *(const uint4*)(sw + (off2>>7)*132 + (off2&127));
        *(uint4*)(gh + off2) = v;
      }
    }
    LGKM_WAIT;
  }
}

// ---------------- mega pass: 32 atoms/block, 2 atoms per 16-lane group --------
// Group cg sweeps atoms base+cg (tile 0) and base+16+cg (tile 1) sequentially
// with the r8-proven shfl-meta gather (per-edge meta register-resident; only
// payload loads on the chain). Block barrier then waits on max over 16 sums of
// TWO segments (variance down ~1.56x -> ~1.31x). Node update loops both tiles.
__global__ __launch_bounds__(256,8) void mega_pass(
  const uint2* __restrict__ meta2, const ushort_t* __restrict__ hin,
  ushort_t* __restrict__ hout, const ushort_t* __restrict__ tab,
  const ushort_t* __restrict__ l2T, const ushort_t* __restrict__ bkT,
  const ushort_t* __restrict__ l1Tn,
  const float* __restrict__ l2b, const float* __restrict__ bb,
  const int* __restrict__ seg, const int* __restrict__ bsum,
  float* __restrict__ x, int do_h)
{
  __shared__ ushort_t nt2[2*2112];      // 8.4 KB: two 16-atom node tiles
  const int wave = threadIdx.x>>6, lane = threadIdx.x&63;
  const int quad = lane>>4, n15 = lane&15;
  const int base = blockIdx.x*ATB;
  const f32x4 zero4 = {0.f,0.f,0.f,0.f};
  const int cg = threadIdx.x >> 4, ctf = threadIdx.x & 15;

  #pragma unroll 1
  for (int q=0; q<2; ++q){
    const int ca = base + q*16 + cg;
    int clo = 0, chi = 0;
    if (ca < NN){
      chi = seg[ca] + bsum[ca>>8];
      clo = (ca==0) ? 0 : (seg[ca-1] + bsum[(ca-1)>>8]);
    }
    float acc[8];
    #pragma unroll
    for (int j=0;j<8;j++) acc[j] = 0.f;

    if (clo < chi){
      const int last = chi - 1;
      const half8* tabc = (const half8*)tab + ctf;   // row i at tabc[i*16]
      const ushort_t* hinc = hin + ctf*8;            // + src*128
      int s0 = clo;
      int cnt = (chi - s0 < 16) ? (chi - s0) : 16;
      int ei0 = s0 + ctf;
      uint2 mm = meta2[(ei0 <= last) ? ei0 : last];
      int ei1 = s0 + 16 + ctf;
      uint2 mq = (s0 + 16 <= last) ? meta2[(ei1 <= last) ? ei1 : last] : mm;
      float fr; half8 w0, w1, hv;
      {
        unsigned mx = __shfl(mm.x, 0, 16);
        unsigned my = __shfl(mm.y, 0, 16);
        float t = __uint_as_float(mx); int i0 = (int)t; fr = t - (float)i0;
        w0 = tabc[(size_t)i0*16];
        w1 = tabc[(size_t)i0*16 + 16];
        hv = *(const half8*)(hinc + (size_t)my*128);
      }
      int j = 0;
      for (;;){
        int jn = j + 1;
        bool more = true;
        if (jn >= cnt){
          if (s0 + 16 > last){ more = false; }
          else {
            s0 += 16;
            cnt = (chi - s0 < 16) ? (chi - s0) : 16;
            mm = mq;
            int ei2 = s0 + 16 + ctf;
            mq = (s0 + 16 <= last) ? meta2[(ei2 <= last) ? ei2 : last] : mm;
            jn = 0;
          }
        }
        float frn = fr; half8 w0n = w0, w1n = w1, hvn = hv;
        if (more){
          unsigned mx = __shfl(mm.x, jn, 16);
          unsigned my = __shfl(mm.y, jn, 16);
          float t = __uint_as_float(mx); int i2 = (int)t; frn = t - (float)i2;
          w0n = tabc[(size_t)i2*16];
          w1n = tabc[(size_t)i2*16 + 16];
          hvn = *(const half8*)(hinc + (size_t)my*128);
        }
        #pragma unroll
        for (int jj=0;jj<8;jj++){
          float wl = (float)w0[jj] + fr * ((float)w1[jj] - (float)w0[jj]);
          acc[jj] += wl * (float)hv[jj];
        }
        if (!more) break;
        w0 = w0n; w1 = w1n; hv = hvn; fr = frn; j = jn;
      }
    }
    // agg (fp16) into node tile q
    union { ushort_t s[8]; uint4 qv; } pk;
    #pragma unroll
    for (int j=0;j<8;j++) pk.s[j] = f2h(acc[j]);
    *(uint4*)(nt2 + q*2112 + cg*132 + ctf*8) = pk.qv;
  }
  __syncthreads();

  // node update: loop over the two 16-atom tiles
  #pragma unroll 1
  for (int t=0; t<2; ++t){
    ushort_t* nt = nt2 + t*2112;
    const int baset = base + t*16;
    const bool vrow = (baset + n15) < NN;
    half8 bg[4];
    #pragma unroll
    for (int ks=0;ks<4;ks++){
      const ushort_t* ra = nt + n15*132 + ks*32 + quad*8;
      union { uint2 v[2]; half8 h16; } cc;
      cc.v[0] = *(const uint2*)(ra);
      cc.v[1] = *(const uint2*)(ra + 4);
      bg[ks] = cc.h16;
    }
    __syncthreads();
    const half8* wAv = (const half8*)l2T;
    f32x4 accA[2];
    #pragma unroll
    for (int i=0;i<2;i++) accA[i] = zero4;
    #pragma unroll
    for (int ks=0;ks<4;ks++){
      #pragma unroll
      for (int i=0;i<2;i++)
        accA[i] = MFMA16(wAv[((wave*2+i)*4+ks)*64 + lane], bg[ks], accA[i]);
    }
    #pragma unroll
    for (int i=0;i<2;i++){
      int mt = wave*2 + i;
      f32x4 bv = *(const f32x4*)(l2b + mt*16 + quad*4);
      union { ushort_t s[4]; uint2 v; } pk;
      #pragma unroll
      for (int r=0;r<4;r++) pk.s[r] = f2h(fast_tanh(accA[i][r] + bv[r]));
      *(uint2*)(nt + n15*132 + mt*16 + quad*4) = pk.v;
    }
    __syncthreads();
    half8 bg2[4];
    #pragma unroll
    for (int ks=0;ks<4;ks++){
      const ushort_t* ra = nt + n15*132 + ks*32 + quad*8;
      union { uint2 v[2]; half8 h16; } cc;
      cc.v[0] = *(const uint2*)(ra);
      cc.v[1] = *(const uint2*)(ra + 4);
      bg2[ks] = cc.h16;
    }
    __syncthreads();
    const half8* wBv = (const half8*)bkT;
    f32x4 accB[2];
    #pragma unroll
    for (int i=0;i<2;i++) accB[i] = zero4;
    #pragma unroll
    for (int ks=0;ks<4;ks++){
      #pragma unroll
      for (int i=0;i<2;i++)
        accB[i] = MFMA16(wBv[((wave*2+i)*4+ks)*64 + lane], bg2[ks], accB[i]);
    }
    f32x4 xn[2];
    float* xp = x + (size_t)(baset + n15)*128;
    #pragma unroll
    for (int i=0;i<2;i++){
      int mt = wave*2 + i;
      f32x4 bv = *(const f32x4*)(bb + mt*16 + quad*4);
      f32x4 xv = vrow ? *(const f32x4*)(xp + mt*16 + quad*4) : zero4;
      xn[i] = xv + accB[i] + bv;
      if (vrow) *(f32x4*)(xp + mt*16 + quad*4) = xn[i];
    }
    if (do_h){
      #pragma unroll
      for (int i=0;i<2;i++){
        int mt = wave*2 + i;
        union { ushort_t s[4]; uint2 v; } pk;
        #pragma unroll
        for (int r=0;r<4;r++) pk.s[r] = f2h(xn[i][r]);
        *(uint2*)(nt + n15*132 + mt*16 + quad*4) = pk.v;
      }
      __syncthreads();
      half8 bg3[4];
      #pragma unroll
      for (int ks=0;ks<4;ks++){
        const ushort_t* ra = nt + n15*132 + ks*32 + quad*8;
        union { uint2 v[2]; half8 h16; } cc;
        cc.v[0] = *(const uint2*)(ra);
        cc.v[1] = *(const uint2*)(ra + 4);
        bg3[ks] = cc.h16;
      }
      const half8* wCv = (const half8*)l1Tn;
      f32x4 accC[2];
      #pragma unroll
      for (int i=0;i<2;i++) accC[i] = zero4;
      #pragma unroll
      for (int ks=0;ks<4;ks++){
        #pragma unroll
        for (int i=0;i<2;i++)
          accC[i] = MFMA16(wCv[((wave*2+i)*4+ks)*64 + lane], bg3[ks], accC[i]);
      }
      ushort_t* hp = hout + (size_t)(baset + n15)*128;
      #pragma unroll
      for (int i=0;i<2;i++){
        int mt = wave*2 + i;
        union { ushort_t s[4]; uint2 v; } pk;
        #pragma unroll
        for (int r=0;r<4;r++) pk.s[r] = f2h(accC[i][r]);
        if (vrow) *(uint2*)(hp + mt*16 + quad*4) = pk.v;
      }
      __syncthreads();                 // nt reads done before next t overwrites
    } else {
      __syncthreads();
    }
  }
}

// ---------------- fused output head: tanh(x@ow1+b1)@ow2 + ob2, per-mol sum ----
__global__ __launch_bounds__(256) void out_head(
  const float* __restrict__ x, const ushort_t* __restrict__ o1T,
  const float* __restrict__ ob1, const float* __restrict__ ow2,
  const float* __restrict__ ob2, const int* __restrict__ batch,
  float* __restrict__ out)
{
  __shared__ float part[NEXM];
  const int tid = threadIdx.x;
  if (tid < NEXM) part[tid] = 0.f;
  __syncthreads();
  const int wave = tid>>6, lane = tid&63;
  const int quad = lane>>4, n15 = lane&15;
  const half8* wv = (const half8*)o1T;
  const f32x4 zero4 = {0.f,0.f,0.f,0.f};
  f32x4 ow2v[4], ob1v[4];
  #pragma unroll
  for (int mt=0;mt<4;mt++){
    ow2v[mt] = *(const f32x4*)(ow2 + mt*16 + quad*4);
    ob1v[mt] = *(const f32x4*)(ob1 + mt*16 + quad*4);
  }
  const float ob2v = ob2[0];
  const int ntiles = NN/16;
  const int stride = gridDim.x*4;
  for (int tile = blockIdx.x*4 + wave; tile < ntiles; tile += stride){
    int a0 = tile*16;
    half8 bg[4];
    const f32x4* av = (const f32x4*)(x + (size_t)(a0 + n15)*128);
    #pragma unroll
    for (int ks=0;ks<4;ks++){
      f32x4 lo = av[ks*8 + quad*2];
      f32x4 hi = av[ks*8 + quad*2 + 1];
      half8 bh;
      #pragma unroll
      for (int i=0;i<4;i++){ bh[i]=(_Float16)lo[i]; bh[4+i]=(_Float16)hi[i]; }
      bg[ks] = bh;
    }
    f32x4 acc[4];
    #pragma unroll
    for (int mt=0;mt<4;mt++) acc[mt] = zero4;
    #pragma unroll
    for (int ks=0;ks<4;ks++){
      #pragma unroll
      for (int mt=0;mt<4;mt++) acc[mt] = MFMA16(wv[(mt*4+ks)*64 + lane], bg[ks], acc[mt]);
    }
    float e = 0.f;
    #pragma unroll
    for (int mt=0;mt<4;mt++){
      f32x4 v = acc[mt] + ob1v[mt];
      #pragma unroll
      for (int r=0;r<4;r++) e += fast_tanh(v[r]) * ow2v[mt][r];
    }
    e += __shfl_xor(e, 16, 64);
    e += __shfl_xor(e, 32, 64);
    if (quad == 0){
      int a = a0 + n15;
      LDS_ADD(&part[batch[a]], e + ob2v);
    }
  }
  __syncthreads();
  if (tid < NEXM)
    __hip_atomic_fetch_add(out + tid, part[tid], __ATOMIC_RELAXED, __HIP_MEMORY_SCOPE_AGENT);
}

// ---------------- host orchestration ------------------------------------------
extern "C" void kernel_launch(void* const* d_in, const int* in_sizes, int n_in,
                              void* d_out, int out_size, void* d_ws, size_t ws_size,
                              hipStream_t stream)
{
  const float* pos  = (const float*)d_in[0];
  const int*   atyp = (const int*)  d_in[1];
  const int*   ei   = (const int*)  d_in[2];
  const int*   bat  = (const int*)  d_in[3];
  const float* emb  = (const float*)d_in[4];
  const float* fw1  = (const float*)d_in[5];
  const float* fb1  = (const float*)d_in[6];
  const float* fw2  = (const float*)d_in[7];
  const float* fb2  = (const float*)d_in[8];
  const float* l1w  = (const float*)d_in[9];
  const float* l2w  = (const float*)d_in[10];
  const float* l2b  = (const float*)d_in[11];
  const float* bw   = (const float*)d_in[12];
  const float* bb   = (const float*)d_in[13];
  const float* ow1  = (const float*)d_in[14];
  const float* ob1  = (const float*)d_in[15];
  const float* ow2  = (const float*)d_in[16];
  const float* ob2  = (const float*)d_in[17];
  float* out = (float*)d_out;

  char* p = (char*)d_ws;
  uint2*    meta2 = (uint2*)p;   p += (size_t)EE*8;      //  3.84 MB {t, src}
  ushort_t* hA   = (ushort_t*)p; p += (size_t)NN*128*2;  //  7.68 MB
  ushort_t* hB   = (ushort_t*)p; p += (size_t)NN*128*2;  //  7.68 MB
  float*    x    = (float*)p;    p += (size_t)NN*128*4;  // 15.36 MB
  ushort_t* frags = (ushort_t*)p; p += 229376*2;         //  0.46 MB
  int*      seg  = (int*)p;      p += (size_t)NN*4;      //  0.12 MB
  int*      bsum = (int*)p;      p += 512;               //  tiny
  ushort_t* tab  = (ushort_t*)p; p += (size_t)3*TROWS*128*2; // 1.59 MB W(d) tables

  // aliased scratch: cnt lives in x (dead before embed branch writes x)
  int* cnt = (int*)x;

  ushort_t* w1T = frags;                 // 3 x 8192
  ushort_t* w2T = frags + 24576;         // 3 x 16384
  ushort_t* l2T = frags + 73728;         // 3 x 16384
  ushort_t* bkT = frags + 122880;        // 3 x 16384
  ushort_t* l1T = frags + 172032;        // 3 x 16384
  ushort_t* o1T = frags + 221184;        // 8192

  hipMemsetAsync(cnt, 0, NN*sizeof(int), stream);
  fused_prep<<<896+1875,256,0,stream>>>(fw1,fb1,fw2,l1w,l2w,bw,ow1,frags,ei,cnt,out);
  fused_mid<<<99+NSB,256,0,stream>>>(w1T, w2T, fb2, tab, cnt, seg, bsum);
  scan2<<<1,128,0,stream>>>(bsum);
  fused_tail<<<1875+512,256,0,stream>>>(pos, ei, seg, bsum, meta2,
                                        atyp, emb, l1T, x, hA);

  for (int b=0;b<3;b++){
    const ushort_t* hin = (b & 1) ? hB : hA;
    ushort_t*       hoB = (b & 1) ? hA : hB;
    int do_h = (b < 2) ? 1 : 0;
    mega_pass<<<NBLK,256,0,stream>>>(meta2, hin, hoB,
                                     tab + (size_t)b*TROWS*128,
                                     l2T + b*16384, bkT + b*16384,
                                     l1T + ((b<2)?(b+1):0)*16384,
                                     l2b + b*128, bb + b*128,
                                     seg, bsum, x, do_h);
  }
  out_head<<<256,256,0,stream>>>(x, o1T, ob1, ow2, ob2, bat, out);
}

// Round 11
// 291.620 us; speedup vs baseline: 1.3182x; 1.3182x over previous
//
#include <hip/hip_runtime.h>

typedef unsigned short ushort_t;
typedef _Float16 half8 __attribute__((ext_vector_type(8)));
typedef float f32x4 __attribute__((ext_vector_type(4)));

constexpr int NN  = 30000;
constexpr int EE  = 480000;
constexpr int NEXM = 64;
constexpr int ATB = 16;                 // dst atoms owned per mega_pass block
constexpr int NSB = (NN + 255) / 256;   // scan blocks (118)
constexpr int NBINS = 2048;             // W(d) table bins over [0,10]
constexpr int TROWS = 2064;             // 129 tiles * 16 rows (>= NBINS+2)

#define MFMA16(a,b,c) __builtin_amdgcn_mfma_f32_16x16x32_f16((a),(b),(c),0,0,0)
#define LDS_ADD(p,v) __hip_atomic_fetch_add((p),(v),__ATOMIC_RELAXED,__HIP_MEMORY_SCOPE_WORKGROUP)
#define LGKM_WAIT asm volatile("s_waitcnt lgkmcnt(0)" ::: "memory")

__device__ __forceinline__ float fast_tanh(float x){
  float e2 = __builtin_amdgcn_exp2f(x * 2.885390081777927f);
  return 1.f - 2.f * __builtin_amdgcn_rcpf(e2 + 1.f);
}
__device__ __forceinline__ ushort_t f2h(float v){
  union { _Float16 h; ushort_t s; } cv; cv.h = (_Float16)v; return cv.s;
}

// ---------------- F1: weight pre-swizzle  ||  edge histogram  ||  zero out ----
__global__ __launch_bounds__(256) void fused_prep(
  const float* __restrict__ fw1, const float* __restrict__ fb1,
  const float* __restrict__ fw2, const float* __restrict__ l1w,
  const float* __restrict__ l2w, const float* __restrict__ bw,
  const float* __restrict__ ow1, ushort_t* __restrict__ frags,
  const int* __restrict__ ei, int* __restrict__ cnt, float* __restrict__ out)
{
  const int bid = blockIdx.x;
  if (bid < 896){
    if (bid == 0 && threadIdx.x < NEXM) out[threadIdx.x] = 0.f;
    int u = bid*256 + threadIdx.x;
    float val;
    if (u < 24576){                       // w1T A-frags, K padded 50->64, row50=bias
      int b = u >> 13; int v = u & 8191;
      int j = v & 7, lane = (v>>3)&63, fid = v>>9;     // fid = mt*2+ks
      int mt = fid>>1, ks = fid&1;
      int f1 = mt*16 + (lane&15);
      int k  = ks*32 + ((lane>>4)&3)*8 + j;
      val = (k < 50) ? fw1[(b*50 + k)*128 + f1] : (k == 50 ? fb1[b*128 + f1] : 0.f);
    } else if (u < 73728){                // w2T A-frags (A[m=f2][k=f1]), fid = mt*4+ks
      int v = u - 24576; int b = v >> 14; int v2 = v & 16383;
      int j = v2&7, lane = (v2>>3)&63, fid = v2>>9;
      int mt = fid>>2, ks = fid&3;
      int n = mt*16 + (lane&15);          // f2
      int k = ks*32 + ((lane>>4)&3)*8 + j; // f1
      val = fw2[b*16384 + k*128 + n];
    } else if (u < 221184){               // l2T / blkT / l1T A-frags, fid = mt*4+ks
      int v = u - 73728; int g = v / 49152; int v1 = v - g*49152;
      int b = v1 >> 14; int v2 = v1 & 16383;
      int j = v2&7, lane=(v2>>3)&63, fid=v2>>9;
      int mt = fid>>2, ks = fid&3;
      int n = mt*16 + (lane&15);
      int k = ks*32 + ((lane>>4)&3)*8 + j;
      const float* W = (g==0? l2w : (g==1? bw : l1w));
      val = W[b*16384 + k*128 + n];
    } else {                              // ow1T A-frags [128x64], fid = mt*4+ks
      int v2 = u - 221184;
      int j = v2&7, lane=(v2>>3)&63, fid=v2>>9;
      int mt = fid>>2, ks = fid&3;
      int n = mt*16 + (lane&15);
      int k = ks*32 + ((lane>>4)&3)*8 + j;
      val = ow1[k*64 + n];
    }
    frags[u] = f2h(val);
  } else {
    int e = (bid-896)*256 + threadIdx.x;
    atomicAdd(cnt + ei[EE + e], 1);
  }
}

// ---------------- F2: W(d) table build  ||  scan stage 1 ----------------------
__global__ __launch_bounds__(256) void fused_mid(
  const ushort_t* __restrict__ w1a, const ushort_t* __restrict__ w2a,
  const float* __restrict__ fb2, ushort_t* __restrict__ tab,
  const int* __restrict__ cnt, int* __restrict__ seg, int* __restrict__ bsum)
{
  __shared__ ushort_t st[4*2112];
  const int bid = blockIdx.x;
  if (bid < 99){
    const int wave = threadIdx.x>>6, lane = threadIdx.x&63;
    const int quad = lane>>4, n15 = lane&15;
    const int b = bid / 33, tg = bid % 33;
    const int tile = tg*4 + wave;
    if (tile >= TROWS/16) return;
    const half8* w1v = (const half8*)(w1a + b*8192);
    const half8* w2v = (const half8*)(w2a + b*16384);
    ushort_t* tw = st + wave*2112;
    half8 a1[16];
    #pragma unroll
    for (int i=0;i<16;i++) a1[i] = w1v[i*64 + lane];
    f32x4 b2v[8];
    #pragma unroll
    for (int mt=0;mt<8;mt++) b2v[mt] = *(const f32x4*)(fb2 + b*128 + mt*16 + quad*4);
    const f32x4 zero4 = {0.f,0.f,0.f,0.f};
    const float dd = 10.f/49.f;
    const float coefl2 = (-0.5f/(dd*dd)) * 1.4426950408889634f;
    const float dbin = 10.f/(float)NBINS;

    float de = (float)(tile*16 + n15) * dbin;
    float Cv = (de < 10.f) ? 0.5f*(cosf(de*0.31415926535897931f)+1.f) : 0.f;
    half8 rb0, rb1;
    #pragma unroll
    for (int j=0;j<8;j++){
      int k0 = quad*8 + j;
      float t0 = de - (float)k0*dd;
      rb0[j] = (_Float16)__builtin_amdgcn_exp2f(coefl2*t0*t0);
      int k1 = 32 + quad*8 + j;
      float v1;
      if (k1 < 50){ float t1 = de - (float)k1*dd; v1 = __builtin_amdgcn_exp2f(coefl2*t1*t1); }
      else v1 = (k1 == 50) ? 1.f : 0.f;
      rb1[j] = (_Float16)v1;
    }
    f32x4 acc1[8];
    #pragma unroll
    for (int mt=0;mt<8;mt++){
      acc1[mt] = MFMA16(a1[mt*2],   rb0, zero4);
      acc1[mt] = MFMA16(a1[mt*2+1], rb1, acc1[mt]);
    }
    #pragma unroll
    for (int mt=0;mt<8;mt++){
      union { ushort_t s[4]; uint2 v; } pk;
      #pragma unroll
      for (int r=0;r<4;r++) pk.s[r] = f2h(fast_tanh(acc1[mt][r]));
      *(uint2*)(tw + n15*132 + mt*16 + quad*4) = pk.v;
    }
    LGKM_WAIT;
    f32x4 acc2[8];
    #pragma unroll
    for (int mt=0;mt<8;mt++) acc2[mt] = zero4;
    #pragma unroll
    for (int ks=0;ks<4;ks++){
      const ushort_t* ra = tw + n15*132 + ks*32 + quad*8;
      union { uint2 v[2]; half8 h16; } cc;
      cc.v[0] = *(const uint2*)(ra);
      cc.v[1] = *(const uint2*)(ra + 4);
      half8 tb = cc.h16;
      #pragma unroll
      for (int mt=0;mt<8;mt++) acc2[mt] = MFMA16(w2v[(mt*4+ks)*64 + lane], tb, acc2[mt]);
    }
    LGKM_WAIT;
    #pragma unroll
    for (int mt=0;mt<8;mt++){
      f32x4 v = acc2[mt] + b2v[mt];
      union { ushort_t s[4]; uint2 q; } pk;
      #pragma unroll
      for (int r=0;r<4;r++) pk.s[r] = f2h(v[r] * Cv);
      *(uint2*)(tw + n15*132 + mt*16 + quad*4) = pk.q;
    }
    LGKM_WAIT;
    ushort_t* dstb = tab + ((size_t)tile*16)*128 + (size_t)b*TROWS*128;
    #pragma unroll
    for (int it=0;it<4;it++){
      int off = it*512 + lane*8;
      uint4 v = *(const uint4*)(tw + (off>>7)*132 + (off&127));
      *(uint4*)(dstb + (size_t)(off>>7)*128 + (off&127)) = v;
    }
  } else {
    // scan1 on block sb = bid-99
    int* ws = (int*)st;
    const int sb = bid - 99;
    int i = sb*256 + threadIdx.x;
    int lane = threadIdx.x & 63, w = threadIdx.x >> 6;
    int v = (i < NN) ? cnt[i] : 0;
    int s = v;
    #pragma unroll
    for (int o=1;o<64;o<<=1){ int t = __shfl_up(s,o,64); if (lane>=o) s += t; }
    if (lane == 63) ws[w] = s;
    __syncthreads();
    int add = 0;
    #pragma unroll
    for (int j=0;j<3;j++) if (w > j) add += ws[j];
    s += add;
    if (i < NN) seg[i] = s - v;
    if (threadIdx.x == 255) bsum[sb] = s;
  }
}

// stage 2: one block scans the 118 block totals -> exclusive offsets (in place)
__global__ __launch_bounds__(128) void scan2(int* __restrict__ bsum)
{
  __shared__ int w0tot;
  int tid = threadIdx.x, lane = tid & 63, w = tid >> 6;
  int v = (tid < NSB) ? bsum[tid] : 0;
  int s = v;
  #pragma unroll
  for (int o=1;o<64;o<<=1){ int t = __shfl_up(s,o,64); if (lane>=o) s += t; }
  if (w == 0 && lane == 63) w0tot = s;
  __syncthreads();
  if (w == 1) s += w0tot;
  if (tid < NSB) bsum[tid] = s - v;
}

__global__ __launch_bounds__(256) void scan3(
  int* __restrict__ seg, const int* __restrict__ bsum)
{
  int i = blockIdx.x*256 + threadIdx.x;
  if (i < NN) seg[i] += bsum[blockIdx.x];
}

// ---------------- F3: scatter_meta  ||  embed_h0 ------------------------------
__global__ __launch_bounds__(256) void fused_tail(
  const float* __restrict__ pos, const int* __restrict__ ei,
  int* __restrict__ off, uint2* __restrict__ meta2,
  const int* __restrict__ atype, const float* __restrict__ emb,
  const ushort_t* __restrict__ l1T, float* __restrict__ x, ushort_t* __restrict__ h)
{
  __shared__ float xbuf[4*2112];        // used by embed branch only
  const int bid = blockIdx.x;
  if (bid < 1875){
    int e = bid*256 + threadIdx.x;
    int s = ei[e], d = ei[EE + e];
    float dx = pos[s*3+0]-pos[d*3+0];
    float dy = pos[s*3+1]-pos[d*3+1];
    float dz = pos[s*3+2]-pos[d*3+2];
    float dist = sqrtf(dx*dx+dy*dy+dz*dz + 1e-12f);
    float t = fminf(dist, 10.f) * ((float)NBINS / 10.f);
    int p = atomicAdd(off + d, 1);
    uint2 m;
    m.x = __float_as_uint(t);
    m.y = (unsigned)s;
    meta2[p] = m;
    return;
  }
  const int vb = bid - 1875;            // 0..511
  const int wave = threadIdx.x>>6, lane = threadIdx.x&63;
  const int quad = lane>>4, n15 = lane&15;
  float* xw = xbuf + wave*2112;
  ushort_t* sw = (ushort_t*)xw;
  const half8* wv = (const half8*)l1T;
  const f32x4 zero4 = {0.f,0.f,0.f,0.f};
  const int ntiles = NN/16;
  const int stride = 512*4;
  for (int tile = vb*4 + wave; tile < ntiles; tile += stride){
    int a0 = tile*16;
    int typ = atype[a0 + n15];
    const f32x4* av = (const f32x4*)(emb + (size_t)typ*128);
    half8 bg[4]; f32x4 xl[4], xh[4];
    #pragma unroll
    for (int ks=0;ks<4;ks++){
      f32x4 lo = av[ks*8 + quad*2];
      f32x4 hi = av[ks*8 + quad*2 + 1];
      xl[ks] = lo; xh[ks] = hi;
      half8 bh;
      #pragma unroll
      for (int i=0;i<4;i++){ bh[i]=(_Float16)lo[i]; bh[4+i]=(_Float16)hi[i]; }
      bg[ks] = bh;
    }
    f32x4 acc[8];
    #pragma unroll
    for (int mt=0;mt<8;mt++) acc[mt] = zero4;
    #pragma unroll
    for (int ks=0;ks<4;ks++){
      #pragma unroll
      for (int mt=0;mt<8;mt++) acc[mt] = MFMA16(wv[(mt*4+ks)*64 + lane], bg[ks], acc[mt]);
    }
    #pragma unroll
    for (int ks=0;ks<4;ks++){
      *(f32x4*)(xw + n15*132 + ks*32 + quad*8)     = xl[ks];
      *(f32x4*)(xw + n15*132 + ks*32 + quad*8 + 4) = xh[ks];
    }
    LGKM_WAIT;
    {
      float* gx = x + (size_t)a0*128;
      #pragma unroll
      for (int it=0;it<8;it++){
        int off2 = it*256 + lane*4;
        f32x4 v = *(const f32x4*)(xw + (off2>>7)*132 + (off2&127));
        *(f32x4*)(gx + off2) = v;
      }
    }
    LGKM_WAIT;
    #pragma unroll
    for (int mt=0;mt<8;mt++){
      union { ushort_t s[4]; uint2 v; } pk;
      #pragma unroll
      for (int r=0;r<4;r++) pk.s[r] = f2h(acc[mt][r]);
      *(uint2*)(sw + n15*132 + mt*16 + quad*4) = pk.v;
    }
    LGKM_WAIT;
    {
      ushort_t* gh = h + (size_t)a0*128;
      #pragma unroll
      for (int it=0;it<4;it++){
        int off2 = it*512 + lane*8;
        uint4 v = *(const uint4*)(sw + (off2>>7)*132 + (off2&127));
        *(uint4*)(gh + off2) = v;
      }
    }
    LGKM_WAIT;
  }
}

// ---------------- mega pass: shfl-meta gather (champion, 45.3 us) -------------
// 16-lane group per atom. Lane ctf holds meta for edge s0+ctf of its group's
// current 16-edge batch (one coalesced load per batch; next batch pre-issued a
// full batch ahead). Per-edge meta via __shfl(mm, j, 16) -- register-only, so
// each iteration's chain is payload loads only. Depth-1 payload prefetch.
// Gather body exists ONCE, straight-line at block scope (loop-nesting it
// causes scratch spill -- r9 lesson).
__global__ __launch_bounds__(256,8) void mega_pass(
  const uint2* __restrict__ meta2, const ushort_t* __restrict__ hin,
  ushort_t* __restrict__ hout, const ushort_t* __restrict__ tab,
  const ushort_t* __restrict__ l2T, const ushort_t* __restrict__ bkT,
  const ushort_t* __restrict__ l1Tn,
  const float* __restrict__ l2b, const float* __restrict__ bb,
  const int* __restrict__ segend, float* __restrict__ x, int do_h)
{
  __shared__ ushort_t nt[2112];         // 4.2 KB node tile
  const int wave = threadIdx.x>>6, lane = threadIdx.x&63;
  const int quad = lane>>4, n15 = lane&15;
  const int base = blockIdx.x*ATB;
  const f32x4 zero4 = {0.f,0.f,0.f,0.f};

  // gather: 16-lane group cg owns atom base+cg, feature chunk ctf*8
  const int cg = threadIdx.x >> 4, ctf = threadIdx.x & 15;
  const int ca = base + cg;
  const int clo = (ca==0) ? 0 : segend[ca-1];
  const int chi = segend[ca];
  float acc[8];
  #pragma unroll
  for (int j=0;j<8;j++) acc[j] = 0.f;

  if (clo < chi){
    const int last = chi - 1;
    const half8* tabc = (const half8*)tab + ctf;   // row i at tabc[i*16]
    const ushort_t* hinc = hin + ctf*8;            // + src*128
    int s0 = clo;
    int cnt = (chi - s0 < 16) ? (chi - s0) : 16;
    // batch meta: lane ctf holds edge s0+ctf (clamped dups never consumed)
    int ei0 = s0 + ctf;
    uint2 mm = meta2[(ei0 <= last) ? ei0 : last];
    // next batch pre-issued a full batch ahead
    int ei1 = s0 + 16 + ctf;
    uint2 mq = (s0 + 16 <= last) ? meta2[(ei1 <= last) ? ei1 : last] : mm;
    // payload for edge 0 of batch
    float fr; half8 w0, w1, hv;
    {
      unsigned mx = __shfl(mm.x, 0, 16);
      unsigned my = __shfl(mm.y, 0, 16);
      float t = __uint_as_float(mx); int i0 = (int)t; fr = t - (float)i0;
      w0 = tabc[(size_t)i0*16];
      w1 = tabc[(size_t)i0*16 + 16];
      hv = *(const half8*)(hinc + (size_t)my*128);
    }
    int j = 0;
    for (;;){
      // ---- prefetch next edge's payload (register-resident meta only) ----
      int jn = j + 1;
      bool more = true;
      if (jn >= cnt){
        if (s0 + 16 > last){ more = false; }
        else {
          s0 += 16;
          cnt = (chi - s0 < 16) ? (chi - s0) : 16;
          mm = mq;
          int ei2 = s0 + 16 + ctf;
          mq = (s0 + 16 <= last) ? meta2[(ei2 <= last) ? ei2 : last] : mm;
          jn = 0;
        }
      }
      float frn = fr; half8 w0n = w0, w1n = w1, hvn = hv;
      if (more){
        unsigned mx = __shfl(mm.x, jn, 16);
        unsigned my = __shfl(mm.y, jn, 16);
        float t = __uint_as_float(mx); int i2 = (int)t; frn = t - (float)i2;
        w0n = tabc[(size_t)i2*16];
        w1n = tabc[(size_t)i2*16 + 16];
        hvn = *(const half8*)(hinc + (size_t)my*128);
      }
      // ---- consume current edge ----
      #pragma unroll
      for (int jj=0;jj<8;jj++){
        float wl = (float)w0[jj] + fr * ((float)w1[jj] - (float)w0[jj]);
        acc[jj] += wl * (float)hv[jj];
      }
      if (!more) break;
      w0 = w0n; w1 = w1n; hv = hvn; fr = frn; j = jn;
    }
  }

  // agg tile (fp16) into LDS node tile
  {
    union { ushort_t s[8]; uint4 q; } pk;
    #pragma unroll
    for (int j=0;j<8;j++) pk.s[j] = f2h(acc[j]);
    *(uint4*)(nt + cg*132 + ctf*8) = pk.q;
  }
  __syncthreads();

  // node update for this block's 16-atom tile
  {
    half8 bg[4];
    #pragma unroll
    for (int ks=0;ks<4;ks++){
      const ushort_t* ra = nt + n15*132 + ks*32 + quad*8;
      union { uint2 v[2]; half8 h16; } cc;
      cc.v[0] = *(const uint2*)(ra);
      cc.v[1] = *(const uint2*)(ra + 4);
      bg[ks] = cc.h16;
    }
    __syncthreads();
    const half8* wAv = (const half8*)l2T;
    f32x4 accA[2];
    #pragma unroll
    for (int i=0;i<2;i++) accA[i] = zero4;
    #pragma unroll
    for (int ks=0;ks<4;ks++){
      #pragma unroll
      for (int i=0;i<2;i++)
        accA[i] = MFMA16(wAv[((wave*2+i)*4+ks)*64 + lane], bg[ks], accA[i]);
    }
    #pragma unroll
    for (int i=0;i<2;i++){
      int mt = wave*2 + i;
      f32x4 bv = *(const f32x4*)(l2b + mt*16 + quad*4);
      union { ushort_t s[4]; uint2 v; } pk;
      #pragma unroll
      for (int r=0;r<4;r++) pk.s[r] = f2h(fast_tanh(accA[i][r] + bv[r]));
      *(uint2*)(nt + n15*132 + mt*16 + quad*4) = pk.v;
    }
    __syncthreads();
    half8 bg2[4];
    #pragma unroll
    for (int ks=0;ks<4;ks++){
      const ushort_t* ra = nt + n15*132 + ks*32 + quad*8;
      union { uint2 v[2]; half8 h16; } cc;
      cc.v[0] = *(const uint2*)(ra);
      cc.v[1] = *(const uint2*)(ra + 4);
      bg2[ks] = cc.h16;
    }
    __syncthreads();
    const half8* wBv = (const half8*)bkT;
    f32x4 accB[2];
    #pragma unroll
    for (int i=0;i<2;i++) accB[i] = zero4;
    #pragma unroll
    for (int ks=0;ks<4;ks++){
      #pragma unroll
      for (int i=0;i<2;i++)
        accB[i] = MFMA16(wBv[((wave*2+i)*4+ks)*64 + lane], bg2[ks], accB[i]);
    }
    f32x4 xn[2];
    float* xp = x + (size_t)(base + n15)*128;
    #pragma unroll
    for (int i=0;i<2;i++){
      int mt = wave*2 + i;
      f32x4 bv = *(const f32x4*)(bb + mt*16 + quad*4);
      f32x4 xv = *(const f32x4*)(xp + mt*16 + quad*4);
      xn[i] = xv + accB[i] + bv;
      *(f32x4*)(xp + mt*16 + quad*4) = xn[i];
    }
    if (do_h){
      #pragma unroll
      for (int i=0;i<2;i++){
        int mt = wave*2 + i;
        union { ushort_t s[4]; uint2 v; } pk;
        #pragma unroll
        for (int r=0;r<4;r++) pk.s[r] = f2h(xn[i][r]);
        *(uint2*)(nt + n15*132 + mt*16 + quad*4) = pk.v;
      }
      __syncthreads();
      half8 bg3[4];
      #pragma unroll
      for (int ks=0;ks<4;ks++){
        const ushort_t* ra = nt + n15*132 + ks*32 + quad*8;
        union { uint2 v[2]; half8 h16; } cc;
        cc.v[0] = *(const uint2*)(ra);
        cc.v[1] = *(const uint2*)(ra + 4);
        bg3[ks] = cc.h16;
      }
      const half8* wCv = (const half8*)l1Tn;
      f32x4 accC[2];
      #pragma unroll
      for (int i=0;i<2;i++) accC[i] = zero4;
      #pragma unroll
      for (int ks=0;ks<4;ks++){
        #pragma unroll
        for (int i=0;i<2;i++)
          accC[i] = MFMA16(wCv[((wave*2+i)*4+ks)*64 + lane], bg3[ks], accC[i]);
      }
      ushort_t* hp = hout + (size_t)(base + n15)*128;
      #pragma unroll
      for (int i=0;i<2;i++){
        int mt = wave*2 + i;
        union { ushort_t s[4]; uint2 v; } pk;
        #pragma unroll
        for (int r=0;r<4;r++) pk.s[r] = f2h(accC[i][r]);
        *(uint2*)(hp + mt*16 + quad*4) = pk.v;
      }
    }
  }
}

// ---------------- fused output head: tanh(x@ow1+b1)@ow2 + ob2, per-mol sum ----
__global__ __launch_bounds__(256) void out_head(
  const float* __restrict__ x, const ushort_t* __restrict__ o1T,
  const float* __restrict__ ob1, const float* __restrict__ ow2,
  const float* __restrict__ ob2, const int* __restrict__ batch,
  float* __restrict__ out)
{
  __shared__ float part[NEXM];
  const int tid = threadIdx.x;
  if (tid < NEXM) part[tid] = 0.f;
  __syncthreads();
  const int wave = tid>>6, lane = tid&63;
  const int quad = lane>>4, n15 = lane&15;
  const half8* wv = (const half8*)o1T;
  const f32x4 zero4 = {0.f,0.f,0.f,0.f};
  f32x4 ow2v[4], ob1v[4];
  #pragma unroll
  for (int mt=0;mt<4;mt++){
    ow2v[mt] = *(const f32x4*)(ow2 + mt*16 + quad*4);
    ob1v[mt] = *(const f32x4*)(ob1 + mt*16 + quad*4);
  }
  const float ob2v = ob2[0];
  const int ntiles = NN/16;
  const int stride = gridDim.x*4;
  for (int tile = blockIdx.x*4 + wave; tile < ntiles; tile += stride){
    int a0 = tile*16;
    half8 bg[4];
    const f32x4* av = (const f32x4*)(x + (size_t)(a0 + n15)*128);
    #pragma unroll
    for (int ks=0;ks<4;ks++){
      f32x4 lo = av[ks*8 + quad*2];
      f32x4 hi = av[ks*8 + quad*2 + 1];
      half8 bh;
      #pragma unroll
      for (int i=0;i<4;i++){ bh[i]=(_Float16)lo[i]; bh[4+i]=(_Float16)hi[i]; }
      bg[ks] = bh;
    }
    f32x4 acc[4];
    #pragma unroll
    for (int mt=0;mt<4;mt++) acc[mt] = zero4;
    #pragma unroll
    for (int ks=0;ks<4;ks++){
      #pragma unroll
      for (int mt=0;mt<4;mt++) acc[mt] = MFMA16(wv[(mt*4+ks)*64 + lane], bg[ks], acc[mt]);
    }
    float e = 0.f;
    #pragma unroll
    for (int mt=0;mt<4;mt++){
      f32x4 v = acc[mt] + ob1v[mt];
      #pragma unroll
      for (int r=0;r<4;r++) e += fast_tanh(v[r]) * ow2v[mt][r];
    }
    e += __shfl_xor(e, 16, 64);
    e += __shfl_xor(e, 32, 64);
    if (quad == 0){
      int a = a0 + n15;
      LDS_ADD(&part[batch[a]], e + ob2v);
    }
  }
  __syncthreads();
  if (tid < NEXM)
    __hip_atomic_fetch_add(out + tid, part[tid], __ATOMIC_RELAXED, __HIP_MEMORY_SCOPE_AGENT);
}

// ---------------- host orchestration ------------------------------------------
extern "C" void kernel_launch(void* const* d_in, const int* in_sizes, int n_in,
                              void* d_out, int out_size, void* d_ws, size_t ws_size,
                              hipStream_t stream)
{
  const float* pos  = (const float*)d_in[0];
  const int*   atyp = (const int*)  d_in[1];
  const int*   ei   = (const int*)  d_in[2];
  const int*   bat  = (const int*)  d_in[3];
  const float* emb  = (const float*)d_in[4];
  const float* fw1  = (const float*)d_in[5];
  const float* fb1  = (const float*)d_in[6];
  const float* fw2  = (const float*)d_in[7];
  const float* fb2  = (const float*)d_in[8];
  const float* l1w  = (const float*)d_in[9];
  const float* l2w  = (const float*)d_in[10];
  const float* l2b  = (const float*)d_in[11];
  const float* bw   = (const float*)d_in[12];
  const float* bb   = (const float*)d_in[13];
  const float* ow1  = (const float*)d_in[14];
  const float* ob1  = (const float*)d_in[15];
  const float* ow2  = (const float*)d_in[16];
  const float* ob2  = (const float*)d_in[17];
  float* out = (float*)d_out;

  char* p = (char*)d_ws;
  uint2*    meta2 = (uint2*)p;   p += (size_t)EE*8;      //  3.84 MB {t, src}
  ushort_t* hA   = (ushort_t*)p; p += (size_t)NN*128*2;  //  7.68 MB
  ushort_t* hB   = (ushort_t*)p; p += (size_t)NN*128*2;  //  7.68 MB
  float*    x    = (float*)p;    p += (size_t)NN*128*4;  // 15.36 MB
  ushort_t* frags = (ushort_t*)p; p += 229376*2;         //  0.46 MB
  int*      segend = (int*)p;    p += (size_t)NN*4;      //  0.12 MB
  int*      bsum  = (int*)p;     p += 512;               //  tiny
  ushort_t* tab  = (ushort_t*)p; p += (size_t)3*TROWS*128*2; // 1.59 MB W(d) tables

  // aliased scratch: cnt lives in x (dead before embed branch writes x)
  int* cnt = (int*)x;

  ushort_t* w1T = frags;                 // 3 x 8192
  ushort_t* w2T = frags + 24576;         // 3 x 16384
  ushort_t* l2T = frags + 73728;         // 3 x 16384
  ushort_t* bkT = frags + 122880;        // 3 x 16384
  ushort_t* l1T = frags + 172032;        // 3 x 16384
  ushort_t* o1T = frags + 221184;        // 8192

  hipMemsetAsync(cnt, 0, NN*sizeof(int), stream);
  fused_prep<<<896+1875,256,0,stream>>>(fw1,fb1,fw2,l1w,l2w,bw,ow1,frags,ei,cnt,out);
  fused_mid<<<99+NSB,256,0,stream>>>(w1T, w2T, fb2, tab, cnt, segend, bsum);
  scan2<<<1,128,0,stream>>>(bsum);
  scan3<<<NSB,256,0,stream>>>(segend, bsum);
  fused_tail<<<1875+512,256,0,stream>>>(pos, ei, segend, meta2,
                                        atyp, emb, l1T, x, hA);

  for (int b=0;b<3;b++){
    const ushort_t* hin = (b & 1) ? hB : hA;
    ushort_t*       hoB = (b & 1) ? hA : hB;
    int do_h = (b < 2) ? 1 : 0;
    mega_pass<<<NN/ATB,256,0,stream>>>(meta2, hin, hoB,
                                       tab + (size_t)b*TROWS*128,
                                       l2T + b*16384, bkT + b*16384,
                                       l1T + ((b<2)?(b+1):0)*16384,
                                       l2b + b*128, bb + b*128,
                                       segend, x, do_h);
  }
  out_head<<<256,256,0,stream>>>(x, o1T, ob1, ow2, ob2, bat, out);
}